// Round 6
// baseline (215.732 us; speedup 1.0000x reference)
//
#include <hip/hip_runtime.h>
#include <hip/hip_bf16.h>
#include <stdint.h>
#include <stddef.h>

// MDCT as folded GEMM. out[512, 32784] = D[512,512] . V[512, 32784]
// R5 ABLATION ROUND: R2/R3/R4 sync-structure fixes were all NULL
// (MfmaUtil pinned 14-15%), so per catalog mistake-#8 this round measures
// WHERE the 42 us lives instead of guessing again. gemm_v<STAGE,MFMA,EPI>
// is launched 4x: three diagnostics + the real kernel LAST (correct output
// overwrites diagnostic garbage). Per-dispatch dur comes from rocprof.
//   v_noldst <0,1,1>: no in-loop staging  -> isolates ds_read+MFMA+epi path
//   v_nomfma <1,0,1>: no compute          -> isolates staging+barrier path
//   v_noepi  <1,1,0>: no C-write (acc kept live via asm sink, rule #17)
//   v_full   <1,1,1>: the R4 kernel, unchanged semantics
// Precision: single fp16 product; absmax 0.03125 vs threshold 0.1069.

constexpr int N_ = 512;
constexpr int T_ = 2048;
constexpr int B_ = 16;
constexpr int LEN = N_ * T_;              // 2^20 per batch
constexpr int FRAMES = T_ + 1;            // 2049
constexpr int COLS = B_ * FRAMES;         // 32784
constexpr int NT_TILES = 257;
constexpr int COLS_PAD = NT_TILES * 128;  // 32896
constexpr int KF = 512;
constexpr int BK = 64;
constexpr int TILE_H = 128 * BK;          // elements per LDS buffer (8192)

typedef __attribute__((ext_vector_type(8))) _Float16 f16x8;
typedef __attribute__((ext_vector_type(4))) _Float16 f16x4;
typedef __attribute__((ext_vector_type(4))) float f32x4;

#define GLD16(gptr, lptr)                                                     \
  __builtin_amdgcn_global_load_lds(                                           \
      (const __attribute__((address_space(1))) unsigned int*)(gptr),          \
      (__attribute__((address_space(3))) unsigned int*)(lptr), 16, 0, 0)

// ---------------- Kernel 1: gather filter -> fp16 D -------------------------
__global__ void prep_filter(const float* __restrict__ f,
                            _Float16* __restrict__ D) {
  int idx = (blockIdx.x * 256 + threadIdx.x) * 4;
  int k = idx >> 9;
  int j = idx & 511;
  int t = (j < 256) ? j : (j + 256);
  const float4 v = *(const float4*)&f[k * 1024 + t];
  f16x4 h = {(_Float16)v.x, (_Float16)v.y, (_Float16)v.z, (_Float16)v.w};
  *(f16x4*)&D[k * KF + j] = h;
}

// ---------------- Kernel 2: fold x -> V fp16, one wave per column -----------
__global__ void fold_x(const float* __restrict__ x, _Float16* __restrict__ V) {
  const int blk = (blockIdx.x & 7) * 1028 + (blockIdx.x >> 3);
  const int c = blk * 4 + (threadIdx.x >> 6);  // 4 columns per block
  const int l = threadIdx.x & 63;
  const bool mi = (l < 32);
  const int j0 = mi ? (l * 8) : (256 + (l - 32) * 8);
  const float sgn = mi ? -1.0f : 1.0f;
  float4 a0 = {0.f, 0.f, 0.f, 0.f}, a1 = {0.f, 0.f, 0.f, 0.f};
  float4 r0 = {0.f, 0.f, 0.f, 0.f}, r1 = {0.f, 0.f, 0.f, 0.f};
  if (c < COLS) {
    int b = (int)((unsigned)c / (unsigned)FRAMES);
    int o = c - b * FRAMES;
    const int lo = b * LEN;
    const int g = lo + o * N_ - N_;            // absolute window start
    const int fb = g + (mi ? j0 : (j0 + 256)); // fwd segment (8 floats)
    const int rb = g + (mi ? (504 - j0) : (1272 - j0)); // rev segment
    if ((unsigned)(fb - lo) <= (unsigned)(LEN - 8)) {
      a0 = *(const float4*)(x + fb);
      a1 = *(const float4*)(x + fb + 4);
    }
    if ((unsigned)(rb - lo) <= (unsigned)(LEN - 8)) {
      r0 = *(const float4*)(x + rb);
      r1 = *(const float4*)(x + rb + 4);
    }
  }
  f16x8 h;
  h[0] = (_Float16)__builtin_fmaf(sgn, r1.w, a0.x);
  h[1] = (_Float16)__builtin_fmaf(sgn, r1.z, a0.y);
  h[2] = (_Float16)__builtin_fmaf(sgn, r1.y, a0.z);
  h[3] = (_Float16)__builtin_fmaf(sgn, r1.x, a0.w);
  h[4] = (_Float16)__builtin_fmaf(sgn, r0.w, a1.x);
  h[5] = (_Float16)__builtin_fmaf(sgn, r0.z, a1.y);
  h[6] = (_Float16)__builtin_fmaf(sgn, r0.y, a1.z);
  h[7] = (_Float16)__builtin_fmaf(sgn, r0.x, a1.w);
  if (c < COLS_PAD) *(f16x8*)&V[(size_t)c * KF + j0] = h;
}

// ---------------- Kernel 3: C = D . V, templated ablation variants ----------
template <bool DO_STAGE, bool DO_MFMA, bool DO_EPI>
__global__ __launch_bounds__(256, 2) void gemm_v(
    const _Float16* __restrict__ D, const _Float16* __restrict__ V,
    float* __restrict__ out) {
  __shared__ __align__(16) _Float16 As0[TILE_H];
  __shared__ __align__(16) _Float16 Bs0[TILE_H];
  __shared__ __align__(16) _Float16 As1[TILE_H];
  __shared__ __align__(16) _Float16 Bs1[TILE_H];

  const int id = blockIdx.x;
  const int xcd = id & 7;
  const int sb = id >> 3;
  const int nt = (sb >> 2) * 8 + xcd;
  if (nt >= NT_TILES) return;
  const int m0 = (sb & 3) * 128;
  const int n0 = nt * 128;

  const int tid = threadIdx.x;
  const int wid = tid >> 6;
  const int lane = tid & 63;
  const int quad = lane >> 4;
  const int l16 = lane & 15;
  const int mw = (wid >> 1) * 64;
  const int nw = (wid & 1) * 64;

  f32x4 acc[4][4];
#pragma unroll
  for (int i = 0; i < 4; ++i)
#pragma unroll
    for (int j = 0; j < 4; ++j) acc[i][j] = (f32x4){0.f, 0.f, 0.f, 0.f};

#define STAGE(AS, BS, KT)                                                     \
  do {                                                                        \
    const int kb_ = (KT) * BK;                                                \
    _Pragma("unroll")                                                         \
    for (int it = 0; it < 4; ++it) {                                          \
      const int S_ = it * 256 + tid;                                          \
      const int r_ = S_ >> 3;                                                 \
      const int c_ = (S_ & 7) ^ (r_ & 7);                                     \
      const int g_ = kb_ + c_ * 8;                                            \
      GLD16(D + (size_t)(m0 + r_) * KF + g_, &(AS)[S_ * 8]);                  \
      GLD16(V + (size_t)(n0 + r_) * KF + g_, &(BS)[S_ * 8]);                  \
    }                                                                         \
  } while (0)

#define COMPUTE(AS, BS)                                                       \
  do {                                                                        \
    _Pragma("unroll")                                                         \
    for (int ko = 0; ko < 2; ++ko) {                                          \
      f16x8 af[4], bf[4];                                                     \
      _Pragma("unroll")                                                       \
      for (int i = 0; i < 4; ++i) {                                           \
        int ra_ = mw + i * 16 + l16;                                          \
        int rb_ = nw + i * 16 + l16;                                          \
        int ca_ = ko * 4 + quad;                                              \
        af[i] = *(const f16x8*)&(AS)[(ra_ * 8 + (ca_ ^ (ra_ & 7))) * 8];      \
        bf[i] = *(const f16x8*)&(BS)[(rb_ * 8 + (ca_ ^ (rb_ & 7))) * 8];      \
      }                                                                       \
      _Pragma("unroll")                                                       \
      for (int i = 0; i < 4; ++i)                                             \
        _Pragma("unroll")                                                     \
        for (int j = 0; j < 4; ++j)                                           \
          acc[i][j] = __builtin_amdgcn_mfma_f32_16x16x32_f16(af[i], bf[j],    \
                                                             acc[i][j],      \
                                                             0, 0, 0);        \
    }                                                                         \
  } while (0)

#define WAITV(N) asm volatile("s_waitcnt vmcnt(" #N ")" ::: "memory")
#define BAR() __builtin_amdgcn_s_barrier()
#define SCHED0() __builtin_amdgcn_sched_barrier(0)

  // Prologue: tile 0 into buf0 (always, so all variants touch D/V).
  STAGE(As0, Bs0, 0);
  if (!DO_STAGE) {  // no in-loop staging: settle now, keep barrier count even
    WAITV(0);
    BAR();
  }

#define STEP(AScur, BScur, ASnxt, BSnxt, KT)                                  \
  do {                                                                        \
    if (DO_STAGE) {                                                           \
      if ((KT) < 7) {                                                         \
        STAGE(ASnxt, BSnxt, (KT) + 1);                                        \
        WAITV(8);                                                             \
      } else {                                                                \
        WAITV(0);                                                             \
      }                                                                       \
      BAR();                                                                  \
    }                                                                         \
    if (DO_MFMA) {                                                            \
      SCHED0();                                                               \
      COMPUTE(AScur, BScur);                                                  \
      SCHED0();                                                               \
    }                                                                         \
    if (DO_STAGE) BAR();                                                      \
  } while (0)

  STEP(As0, Bs0, As1, Bs1, 0);
  STEP(As1, Bs1, As0, Bs0, 1);
  STEP(As0, Bs0, As1, Bs1, 2);
  STEP(As1, Bs1, As0, Bs0, 3);
  STEP(As0, Bs0, As1, Bs1, 4);
  STEP(As1, Bs1, As0, Bs0, 5);
  STEP(As0, Bs0, As1, Bs1, 6);
  STEP(As1, Bs1, As0, Bs0, 7);

#undef STEP
#undef STAGE
#undef COMPUTE
#undef WAITV
#undef BAR
#undef SCHED0

  if (DO_EPI) {
    // Epilogue (verified): C/D layout col = lane&15, row = quad*4 + reg.
#pragma unroll
    for (int i = 0; i < 4; ++i) {
#pragma unroll
      for (int j = 0; j < 4; ++j) {
        int col = n0 + nw + j * 16 + l16;
        if (col < COLS) {
          int b = col / FRAMES;
          int o = col - b * FRAMES;
          int rowb = m0 + mw + i * 16 + quad * 4;
          float* op = out + (size_t)b * N_ * FRAMES + (size_t)rowb * FRAMES + o;
#pragma unroll
          for (int r = 0; r < 4; ++r) op[(size_t)r * FRAMES] = acc[i][j][r];
        }
      }
    }
  } else {
    // Rule #17: keep acc live so the MFMA chain isn't DCE'd.
#pragma unroll
    for (int i = 0; i < 4; ++i)
#pragma unroll
      for (int j = 0; j < 4; ++j)
#pragma unroll
        for (int r = 0; r < 4; ++r)
          asm volatile("" ::"v"(acc[i][j][r]));
  }
}

// ---------------- Fallback: direct fp32 conv (if ws too small) --------------
__global__ void naive_conv(const float* __restrict__ x, const float* __restrict__ f,
                           float* __restrict__ out) {
  int col = blockIdx.x;
  int k = threadIdx.x;
  __shared__ float win[1024];
  int b = col / FRAMES;
  int o = col - b * FRAMES;
  const float* xb = x + (size_t)b * LEN;
  int g = o * N_ - N_;
  for (int t = threadIdx.x; t < 1024; t += 512) {
    int i = g + t;
    win[t] = (i >= 0 && i < LEN) ? xb[i] : 0.0f;
  }
  __syncthreads();
  float s = 0.0f;
  const float* fk = f + (size_t)k * 1024;
  for (int t = 0; t < 1024; ++t) s += win[t] * fk[t];
  out[(size_t)b * N_ * FRAMES + (size_t)k * FRAMES + o] = s;
}

extern "C" void kernel_launch(void* const* d_in, const int* in_sizes, int n_in,
                              void* d_out, int out_size, void* d_ws, size_t ws_size,
                              hipStream_t stream) {
  const float* x = (const float*)d_in[0];
  const float* f = (const float*)d_in[1];
  float* out = (float*)d_out;

  const size_t elems_D = (size_t)512 * 512;
  const size_t elems_V = (size_t)COLS_PAD * KF;
  const size_t need = (elems_D + elems_V) * sizeof(_Float16);

  if (ws_size < need) {
    naive_conv<<<COLS, 512, 0, stream>>>(x, f, out);
    return;
  }

  _Float16* D = (_Float16*)d_ws;
  _Float16* V = D + elems_D;

  prep_filter<<<256, 256, 0, stream>>>(f, D);
  fold_x<<<COLS_PAD / 4, 256, 0, stream>>>(x, V);

  // --- Ablation diagnostics (outputs garbage/zeros; overwritten below) ---
  gemm_v<false, true, true><<<1056, 256, 0, stream>>>(D, V, out);   // v_noldst
  gemm_v<true, false, true><<<1056, 256, 0, stream>>>(D, V, out);   // v_nomfma
  gemm_v<true, true, false><<<1056, 256, 0, stream>>>(D, V, out);   // v_noepi
  // --- Real kernel LAST: writes the full correct output ---
  gemm_v<true, true, true><<<1056, 256, 0, stream>>>(D, V, out);    // v_full
}

// Round 7
// 144.261 us; speedup vs baseline: 1.4954x; 1.4954x over previous
//
#include <hip/hip_runtime.h>
#include <hip/hip_bf16.h>
#include <stdint.h>
#include <stddef.h>

// MDCT as folded GEMM. out[512, 32784] = D[512,512] . V[512, 32784]
//   V[c][j] = j<256:  x[g+j] - x[g+511-j]
//             j>=256: x[g+j+256] + x[g+1279-j],   g = o*512 - 512 (per batch)
// Precision: single fp16 product; absmax 0.03125 vs threshold 0.1069.
//
// R6 (this session): R5 ablation sum (3 diagnostics ~70us total vs full 41)
// => no single k-loop phase dominates; 3 sync-structure rounds were NULL.
// New suspect confirmed by arithmetic: EPILOGUE stores. Old epi wrote 64-B
// float segments at o = col - b*2049 ≡ -b (mod 16) -> line-misaligned for
// 15/16 batches -> RMW, ~50% write eff -> ~22us of the 41. Fix: LDS-
// transpose epilogue. acc -> Ct[128][128] f32 tile (reuses the 64KB staging
// SMEM, k-loop is done), barrier, then waves stream rows as contiguous
// 256-B spans (lane l -> cols l and 64+l). Straddle/tail blocks (~64/1028)
// keep the old scalar path. Predict gemm 41 -> 28-32us, total ~131us.

constexpr int N_ = 512;
constexpr int T_ = 2048;
constexpr int B_ = 16;
constexpr int LEN = N_ * T_;              // 2^20 per batch
constexpr int FRAMES = T_ + 1;            // 2049
constexpr int COLS = B_ * FRAMES;         // 32784
constexpr int NT_TILES = 257;
constexpr int COLS_PAD = NT_TILES * 128;  // 32896
constexpr int KF = 512;
constexpr int BK = 64;
constexpr int TILE_H = 128 * BK;          // elements per LDS buffer (8192)

typedef __attribute__((ext_vector_type(8))) _Float16 f16x8;
typedef __attribute__((ext_vector_type(4))) _Float16 f16x4;
typedef __attribute__((ext_vector_type(4))) float f32x4;

#define GLD16(gptr, lptr)                                                     \
  __builtin_amdgcn_global_load_lds(                                           \
      (const __attribute__((address_space(1))) unsigned int*)(gptr),          \
      (__attribute__((address_space(3))) unsigned int*)(lptr), 16, 0, 0)

// ---------------- Kernel 1: gather filter -> fp16 D -------------------------
__global__ void prep_filter(const float* __restrict__ f,
                            _Float16* __restrict__ D) {
  int idx = (blockIdx.x * 256 + threadIdx.x) * 4;
  int k = idx >> 9;
  int j = idx & 511;
  int t = (j < 256) ? j : (j + 256);
  const float4 v = *(const float4*)&f[k * 1024 + t];
  f16x4 h = {(_Float16)v.x, (_Float16)v.y, (_Float16)v.z, (_Float16)v.w};
  *(f16x4*)&D[k * KF + j] = h;
}

// ---------------- Kernel 2: fold x -> V fp16, one wave per column -----------
__global__ void fold_x(const float* __restrict__ x, _Float16* __restrict__ V) {
  const int blk = (blockIdx.x & 7) * 1028 + (blockIdx.x >> 3);
  const int c = blk * 4 + (threadIdx.x >> 6);  // 4 columns per block
  const int l = threadIdx.x & 63;
  const bool mi = (l < 32);
  const int j0 = mi ? (l * 8) : (256 + (l - 32) * 8);
  const float sgn = mi ? -1.0f : 1.0f;
  float4 a0 = {0.f, 0.f, 0.f, 0.f}, a1 = {0.f, 0.f, 0.f, 0.f};
  float4 r0 = {0.f, 0.f, 0.f, 0.f}, r1 = {0.f, 0.f, 0.f, 0.f};
  if (c < COLS) {
    int b = (int)((unsigned)c / (unsigned)FRAMES);
    int o = c - b * FRAMES;
    const int lo = b * LEN;
    const int g = lo + o * N_ - N_;            // absolute window start
    const int fb = g + (mi ? j0 : (j0 + 256)); // fwd segment (8 floats)
    const int rb = g + (mi ? (504 - j0) : (1272 - j0)); // rev segment
    if ((unsigned)(fb - lo) <= (unsigned)(LEN - 8)) {
      a0 = *(const float4*)(x + fb);
      a1 = *(const float4*)(x + fb + 4);
    }
    if ((unsigned)(rb - lo) <= (unsigned)(LEN - 8)) {
      r0 = *(const float4*)(x + rb);
      r1 = *(const float4*)(x + rb + 4);
    }
  }
  f16x8 h;
  h[0] = (_Float16)__builtin_fmaf(sgn, r1.w, a0.x);
  h[1] = (_Float16)__builtin_fmaf(sgn, r1.z, a0.y);
  h[2] = (_Float16)__builtin_fmaf(sgn, r1.y, a0.z);
  h[3] = (_Float16)__builtin_fmaf(sgn, r1.x, a0.w);
  h[4] = (_Float16)__builtin_fmaf(sgn, r0.w, a1.x);
  h[5] = (_Float16)__builtin_fmaf(sgn, r0.z, a1.y);
  h[6] = (_Float16)__builtin_fmaf(sgn, r0.y, a1.z);
  h[7] = (_Float16)__builtin_fmaf(sgn, r0.x, a1.w);
  if (c < COLS_PAD) *(f16x8*)&V[(size_t)c * KF + j0] = h;
}

// ---------------- Kernel 3: C = D . V, fp16 MFMA ----------------------------
// 128x128 tile, BK=64 static dbuf, counted-vmcnt 2-phase (R4), 4 waves
// (2x2 of 64x64), 16x16x32 f16. LDS slot = r*8 + (chunk ^ (r&7)).
// Grid: 1056; id -> xcd=id&7, s=id>>3, m=s&3, nt=(s>>2)*8+xcd.
// R6: coalesced LDS-transpose epilogue (see header comment).
__global__ __launch_bounds__(256, 2) void gemm_fold(
    const _Float16* __restrict__ D, const _Float16* __restrict__ V,
    float* __restrict__ out) {
  // One 64 KB block; k-loop uses 4 compile-time-disjoint 16 KB quarters
  // (constant offsets -> AA can disambiguate; R2's failure was runtime
  // bases). Epilogue reuses the whole block as a 128x128 f32 tile.
  __shared__ __align__(16) _Float16 SMEM[4 * TILE_H];
  _Float16* const As0 = SMEM;
  _Float16* const Bs0 = SMEM + TILE_H;
  _Float16* const As1 = SMEM + 2 * TILE_H;
  _Float16* const Bs1 = SMEM + 3 * TILE_H;

  const int id = blockIdx.x;
  const int xcd = id & 7;
  const int sb = id >> 3;
  const int nt = (sb >> 2) * 8 + xcd;
  if (nt >= NT_TILES) return;
  const int m0 = (sb & 3) * 128;
  const int n0 = nt * 128;

  const int tid = threadIdx.x;
  const int wid = tid >> 6;
  const int lane = tid & 63;
  const int quad = lane >> 4;
  const int l16 = lane & 15;
  const int mw = (wid >> 1) * 64;
  const int nw = (wid & 1) * 64;

  f32x4 acc[4][4];
#pragma unroll
  for (int i = 0; i < 4; ++i)
#pragma unroll
    for (int j = 0; j < 4; ++j) acc[i][j] = (f32x4){0.f, 0.f, 0.f, 0.f};

#define STAGE(AS, BS, KT)                                                     \
  do {                                                                        \
    const int kb_ = (KT) * BK;                                                \
    _Pragma("unroll")                                                         \
    for (int it = 0; it < 4; ++it) {                                          \
      const int S_ = it * 256 + tid;   /* LDS slot = uniform base + lane */   \
      const int r_ = S_ >> 3;          /* tile row */                         \
      const int c_ = (S_ & 7) ^ (r_ & 7); /* swizzled global chunk */         \
      const int g_ = kb_ + c_ * 8;                                            \
      GLD16(D + (size_t)(m0 + r_) * KF + g_, &(AS)[S_ * 8]);                  \
      GLD16(V + (size_t)(n0 + r_) * KF + g_, &(BS)[S_ * 8]);                  \
    }                                                                         \
  } while (0)

#define COMPUTE(AS, BS)                                                       \
  do {                                                                        \
    _Pragma("unroll")                                                         \
    for (int ko = 0; ko < 2; ++ko) {                                          \
      f16x8 af[4], bf[4];                                                     \
      _Pragma("unroll")                                                       \
      for (int i = 0; i < 4; ++i) {                                           \
        int ra_ = mw + i * 16 + l16;                                          \
        int rb_ = nw + i * 16 + l16;                                          \
        int ca_ = ko * 4 + quad;                                              \
        af[i] = *(const f16x8*)&(AS)[(ra_ * 8 + (ca_ ^ (ra_ & 7))) * 8];      \
        bf[i] = *(const f16x8*)&(BS)[(rb_ * 8 + (ca_ ^ (rb_ & 7))) * 8];      \
      }                                                                       \
      _Pragma("unroll")                                                       \
      for (int i = 0; i < 4; ++i)                                             \
        _Pragma("unroll")                                                     \
        for (int j = 0; j < 4; ++j)                                           \
          acc[i][j] = __builtin_amdgcn_mfma_f32_16x16x32_f16(af[i], bf[j],    \
                                                             acc[i][j],      \
                                                             0, 0, 0);        \
    }                                                                         \
  } while (0)

#define WAITV(N) asm volatile("s_waitcnt vmcnt(" #N ")" ::: "memory")
#define BAR() __builtin_amdgcn_s_barrier()
#define SCHED0() __builtin_amdgcn_sched_barrier(0)

  // Prologue: fill buffer 0 (tile 0). 8 VMEM in flight.
  STAGE(As0, Bs0, 0);

  // WAITV(8): drain the oldest 8 (tile KT, aged one full iteration); the
  // 8 newest (tile KT+1) stay in flight across both barriers.
#define STEP(AScur, BScur, ASnxt, BSnxt, KT)                                  \
  do {                                                                        \
    if ((KT) < 7) {                                                           \
      STAGE(ASnxt, BSnxt, (KT) + 1);                                          \
      WAITV(8);                                                               \
    } else {                                                                  \
      WAITV(0);                                                               \
    }                                                                         \
    BAR();     /* collective: tile KT fully in LDS */                         \
    SCHED0();                                                                 \
    COMPUTE(AScur, BScur);                                                    \
    SCHED0();                                                                 \
    BAR();     /* all waves done reading -> buffer reusable */                \
  } while (0)

  STEP(As0, Bs0, As1, Bs1, 0);
  STEP(As1, Bs1, As0, Bs0, 1);
  STEP(As0, Bs0, As1, Bs1, 2);
  STEP(As1, Bs1, As0, Bs0, 3);
  STEP(As0, Bs0, As1, Bs1, 4);
  STEP(As1, Bs1, As0, Bs0, 5);
  STEP(As0, Bs0, As1, Bs1, 6);
  STEP(As1, Bs1, As0, Bs0, 7);

#undef STEP
#undef STAGE
#undef COMPUTE
#undef WAITV
#undef BAR
#undef SCHED0

  // ---------------- Epilogue ----------------
  // acc[i][j][r] holds C[m0 + mw + i*16 + quad*4 + r][n0 + nw + j*16 + l16].
  const int bs = n0 / FRAMES;
  const int os = n0 - bs * FRAMES;
  const bool fast = (os + 128 <= FRAMES) && (n0 + 128 <= COLS);

  if (fast) {
    // Dump acc into a 128x128 f32 tile (reuses staging LDS; k-loop done).
    float* Ct = (float*)SMEM;
#pragma unroll
    for (int i = 0; i < 4; ++i) {
#pragma unroll
      for (int j = 0; j < 4; ++j) {
        const int Lr0 = mw + i * 16 + quad * 4;
        const int Lc = nw + j * 16 + l16;
#pragma unroll
        for (int r = 0; r < 4; ++r) Ct[(Lr0 + r) * 128 + Lc] = acc[i][j][r];
      }
    }
    __syncthreads();
    // Stream rows: lane l stores cols l and 64+l -> two contiguous 256-B
    // spans per row, alignment-independent (no RMW on HBM lines).
    float* const obase = out + (size_t)bs * N_ * FRAMES + os;
#pragma unroll 4
    for (int it2 = 0; it2 < 32; ++it2) {
      const int row = wid * 32 + it2;     // local row 0..127
      const int grow = m0 + row;          // global row < 512
      const float v0 = Ct[row * 128 + lane];
      const float v1 = Ct[row * 128 + 64 + lane];
      float* rp = obase + (size_t)grow * FRAMES;
      rp[lane] = v0;
      rp[64 + lane] = v1;
    }
  } else {
    // Straddle/tail blocks (~64/1028): verified scalar path.
#pragma unroll
    for (int i = 0; i < 4; ++i) {
#pragma unroll
      for (int j = 0; j < 4; ++j) {
        int col = n0 + nw + j * 16 + l16;
        if (col < COLS) {
          int b = col / FRAMES;
          int o = col - b * FRAMES;
          int rowb = m0 + mw + i * 16 + quad * 4;
          float* op = out + (size_t)b * N_ * FRAMES + (size_t)rowb * FRAMES + o;
#pragma unroll
          for (int r = 0; r < 4; ++r) op[(size_t)r * FRAMES] = acc[i][j][r];
        }
      }
    }
  }
}

// ---------------- Fallback: direct fp32 conv (if ws too small) --------------
__global__ void naive_conv(const float* __restrict__ x, const float* __restrict__ f,
                           float* __restrict__ out) {
  int col = blockIdx.x;
  int k = threadIdx.x;
  __shared__ float win[1024];
  int b = col / FRAMES;
  int o = col - b * FRAMES;
  const float* xb = x + (size_t)b * LEN;
  int g = o * N_ - N_;
  for (int t = threadIdx.x; t < 1024; t += 512) {
    int i = g + t;
    win[t] = (i >= 0 && i < LEN) ? xb[i] : 0.0f;
  }
  __syncthreads();
  float s = 0.0f;
  const float* fk = f + (size_t)k * 1024;
  for (int t = 0; t < 1024; ++t) s += win[t] * fk[t];
  out[(size_t)b * N_ * FRAMES + (size_t)k * FRAMES + o] = s;
}

extern "C" void kernel_launch(void* const* d_in, const int* in_sizes, int n_in,
                              void* d_out, int out_size, void* d_ws, size_t ws_size,
                              hipStream_t stream) {
  const float* x = (const float*)d_in[0];
  const float* f = (const float*)d_in[1];
  float* out = (float*)d_out;

  const size_t elems_D = (size_t)512 * 512;
  const size_t elems_V = (size_t)COLS_PAD * KF;
  const size_t need = (elems_D + elems_V) * sizeof(_Float16);

  if (ws_size < need) {
    naive_conv<<<COLS, 512, 0, stream>>>(x, f, out);
    return;
  }

  _Float16* D = (_Float16*)d_ws;
  _Float16* V = D + elems_D;

  prep_filter<<<256, 256, 0, stream>>>(f, D);
  fold_x<<<COLS_PAD / 4, 256, 0, stream>>>(x, V);
  // Grid 1056 = 132*8: covers nt=0..256, m=0..3 (max id 1048); tail exits.
  gemm_fold<<<1056, 256, 0, stream>>>(D, V, out);
}

// Round 9
// 139.935 us; speedup vs baseline: 1.5417x; 1.0309x over previous
//
#include <hip/hip_runtime.h>
#include <hip/hip_bf16.h>
#include <stdint.h>
#include <stddef.h>

// MDCT as folded GEMM. out[512, 32784] = D[512,512] . V[512, 32784]
//   V[c][j] = j<256:  x[g+j] - x[g+511-j]
//             j>=256: x[g+j+256] + x[g+1279-j],   g = o*512 - 512 (per batch)
// Precision: single fp16 product; absmax 0.03125 vs threshold 0.1069.
//
// R8: R7 FAILED (absmax 7.33) from a double-deswizzle in the fast epilogue:
// the LDS read Ct[row*128 + (lane^sw)] ALREADY returns element (row,lane)
// (store applied col^sw, read applies it again -> identity), but the global
// store then applied ^sw a third time -> columns permuted for rows with
// row&12 != 0. Fix: store plainly at rp[lane] / rp[64+lane]. Stores are now
// clean contiguous 256-B spans. Everything else (R7 conflict swizzle on the
// Ct dump, s_sleep de-convoy, counted-vmcnt k-loop) kept identical so this
// round reads their counters. Predict: pass, conflicts 493K -> <50K,
// gemm 36-42 us depending on whether the de-convoy helps.

constexpr int N_ = 512;
constexpr int T_ = 2048;
constexpr int B_ = 16;
constexpr int LEN = N_ * T_;              // 2^20 per batch
constexpr int FRAMES = T_ + 1;            // 2049
constexpr int COLS = B_ * FRAMES;         // 32784
constexpr int NT_TILES = 257;
constexpr int COLS_PAD = NT_TILES * 128;  // 32896
constexpr int KF = 512;
constexpr int BK = 64;
constexpr int TILE_H = 128 * BK;          // elements per LDS buffer (8192)

typedef __attribute__((ext_vector_type(8))) _Float16 f16x8;
typedef __attribute__((ext_vector_type(4))) _Float16 f16x4;
typedef __attribute__((ext_vector_type(4))) float f32x4;

#define GLD16(gptr, lptr)                                                     \
  __builtin_amdgcn_global_load_lds(                                           \
      (const __attribute__((address_space(1))) unsigned int*)(gptr),          \
      (__attribute__((address_space(3))) unsigned int*)(lptr), 16, 0, 0)

// ---------------- Kernel 1: gather filter -> fp16 D -------------------------
__global__ void prep_filter(const float* __restrict__ f,
                            _Float16* __restrict__ D) {
  int idx = (blockIdx.x * 256 + threadIdx.x) * 4;
  int k = idx >> 9;
  int j = idx & 511;
  int t = (j < 256) ? j : (j + 256);
  const float4 v = *(const float4*)&f[k * 1024 + t];
  f16x4 h = {(_Float16)v.x, (_Float16)v.y, (_Float16)v.z, (_Float16)v.w};
  *(f16x4*)&D[k * KF + j] = h;
}

// ---------------- Kernel 2: fold x -> V fp16, one wave per column -----------
__global__ void fold_x(const float* __restrict__ x, _Float16* __restrict__ V) {
  const int blk = (blockIdx.x & 7) * 1028 + (blockIdx.x >> 3);
  const int c = blk * 4 + (threadIdx.x >> 6);  // 4 columns per block
  const int l = threadIdx.x & 63;
  const bool mi = (l < 32);
  const int j0 = mi ? (l * 8) : (256 + (l - 32) * 8);
  const float sgn = mi ? -1.0f : 1.0f;
  float4 a0 = {0.f, 0.f, 0.f, 0.f}, a1 = {0.f, 0.f, 0.f, 0.f};
  float4 r0 = {0.f, 0.f, 0.f, 0.f}, r1 = {0.f, 0.f, 0.f, 0.f};
  if (c < COLS) {
    int b = (int)((unsigned)c / (unsigned)FRAMES);
    int o = c - b * FRAMES;
    const int lo = b * LEN;
    const int g = lo + o * N_ - N_;            // absolute window start
    const int fb = g + (mi ? j0 : (j0 + 256)); // fwd segment (8 floats)
    const int rb = g + (mi ? (504 - j0) : (1272 - j0)); // rev segment
    if ((unsigned)(fb - lo) <= (unsigned)(LEN - 8)) {
      a0 = *(const float4*)(x + fb);
      a1 = *(const float4*)(x + fb + 4);
    }
    if ((unsigned)(rb - lo) <= (unsigned)(LEN - 8)) {
      r0 = *(const float4*)(x + rb);
      r1 = *(const float4*)(x + rb + 4);
    }
  }
  f16x8 h;
  h[0] = (_Float16)__builtin_fmaf(sgn, r1.w, a0.x);
  h[1] = (_Float16)__builtin_fmaf(sgn, r1.z, a0.y);
  h[2] = (_Float16)__builtin_fmaf(sgn, r1.y, a0.z);
  h[3] = (_Float16)__builtin_fmaf(sgn, r1.x, a0.w);
  h[4] = (_Float16)__builtin_fmaf(sgn, r0.w, a1.x);
  h[5] = (_Float16)__builtin_fmaf(sgn, r0.z, a1.y);
  h[6] = (_Float16)__builtin_fmaf(sgn, r0.y, a1.z);
  h[7] = (_Float16)__builtin_fmaf(sgn, r0.x, a1.w);
  if (c < COLS_PAD) *(f16x8*)&V[(size_t)c * KF + j0] = h;
}

// ---------------- Kernel 3: C = D . V, fp16 MFMA ----------------------------
// 128x128 tile, BK=64 static dbuf, counted-vmcnt 2-phase (R4), 4 waves
// (2x2 of 64x64), 16x16x32 f16. Grid: 1056; id -> xcd=id&7, s=id>>3,
// m=s&3, nt=(s>>2)*8+xcd. Epilogue: swizzled LDS-transpose (R7/R8).
__global__ __launch_bounds__(256, 2) void gemm_fold(
    const _Float16* __restrict__ D, const _Float16* __restrict__ V,
    float* __restrict__ out) {
  // One 64 KB block; k-loop uses 4 compile-time-disjoint 16 KB quarters.
  // Epilogue reuses the whole block as a swizzled 128x128 f32 tile.
  __shared__ __align__(16) _Float16 SMEM[4 * TILE_H];
  _Float16* const As0 = SMEM;
  _Float16* const Bs0 = SMEM + TILE_H;
  _Float16* const As1 = SMEM + 2 * TILE_H;
  _Float16* const Bs1 = SMEM + 3 * TILE_H;

  const int id = blockIdx.x;
  const int xcd = id & 7;
  const int sb = id >> 3;
  const int nt = (sb >> 2) * 8 + xcd;
  if (nt >= NT_TILES) return;
  const int m0 = (sb & 3) * 128;
  const int n0 = nt * 128;

  // De-convoy: anti-phase half the blocks so co-resident blocks overlap
  // staging with compute instead of hitting the same phase simultaneously.
  if ((id >> 8) & 1) {
    __builtin_amdgcn_s_sleep(15);  // ~960 cyc ~= half a k-iter
  }

  const int tid = threadIdx.x;
  const int wid = tid >> 6;
  const int lane = tid & 63;
  const int quad = lane >> 4;
  const int l16 = lane & 15;
  const int mw = (wid >> 1) * 64;
  const int nw = (wid & 1) * 64;

  f32x4 acc[4][4];
#pragma unroll
  for (int i = 0; i < 4; ++i)
#pragma unroll
    for (int j = 0; j < 4; ++j) acc[i][j] = (f32x4){0.f, 0.f, 0.f, 0.f};

#define STAGE(AS, BS, KT)                                                     \
  do {                                                                        \
    const int kb_ = (KT) * BK;                                                \
    _Pragma("unroll")                                                         \
    for (int it = 0; it < 4; ++it) {                                          \
      const int S_ = it * 256 + tid;   /* LDS slot = uniform base + lane */   \
      const int r_ = S_ >> 3;          /* tile row */                         \
      const int c_ = (S_ & 7) ^ (r_ & 7); /* swizzled global chunk */         \
      const int g_ = kb_ + c_ * 8;                                            \
      GLD16(D + (size_t)(m0 + r_) * KF + g_, &(AS)[S_ * 8]);                  \
      GLD16(V + (size_t)(n0 + r_) * KF + g_, &(BS)[S_ * 8]);                  \
    }                                                                         \
  } while (0)

#define COMPUTE(AS, BS)                                                       \
  do {                                                                        \
    _Pragma("unroll")                                                         \
    for (int ko = 0; ko < 2; ++ko) {                                          \
      f16x8 af[4], bf[4];                                                     \
      _Pragma("unroll")                                                       \
      for (int i = 0; i < 4; ++i) {                                           \
        int ra_ = mw + i * 16 + l16;                                          \
        int rb_ = nw + i * 16 + l16;                                          \
        int ca_ = ko * 4 + quad;                                              \
        af[i] = *(const f16x8*)&(AS)[(ra_ * 8 + (ca_ ^ (ra_ & 7))) * 8];      \
        bf[i] = *(const f16x8*)&(BS)[(rb_ * 8 + (ca_ ^ (rb_ & 7))) * 8];      \
      }                                                                       \
      _Pragma("unroll")                                                       \
      for (int i = 0; i < 4; ++i)                                             \
        _Pragma("unroll")                                                     \
        for (int j = 0; j < 4; ++j)                                           \
          acc[i][j] = __builtin_amdgcn_mfma_f32_16x16x32_f16(af[i], bf[j],    \
                                                             acc[i][j],      \
                                                             0, 0, 0);        \
    }                                                                         \
  } while (0)

#define WAITV(N) asm volatile("s_waitcnt vmcnt(" #N ")" ::: "memory")
#define BAR() __builtin_amdgcn_s_barrier()
#define SCHED0() __builtin_amdgcn_sched_barrier(0)

  // Prologue: fill buffer 0 (tile 0). 8 VMEM in flight.
  STAGE(As0, Bs0, 0);

  // WAITV(8): drain the oldest 8 (tile KT, aged one full iteration); the
  // 8 newest (tile KT+1) stay in flight across both barriers.
#define STEP(AScur, BScur, ASnxt, BSnxt, KT)                                  \
  do {                                                                        \
    if ((KT) < 7) {                                                           \
      STAGE(ASnxt, BSnxt, (KT) + 1);                                          \
      WAITV(8);                                                               \
    } else {                                                                  \
      WAITV(0);                                                               \
    }                                                                         \
    BAR();     /* collective: tile KT fully in LDS */                         \
    SCHED0();                                                                 \
    COMPUTE(AScur, BScur);                                                    \
    SCHED0();                                                                 \
    BAR();     /* all waves done reading -> buffer reusable */                \
  } while (0)

  STEP(As0, Bs0, As1, Bs1, 0);
  STEP(As1, Bs1, As0, Bs0, 1);
  STEP(As0, Bs0, As1, Bs1, 2);
  STEP(As1, Bs1, As0, Bs0, 3);
  STEP(As0, Bs0, As1, Bs1, 4);
  STEP(As1, Bs1, As0, Bs0, 5);
  STEP(As0, Bs0, As1, Bs1, 6);
  STEP(As1, Bs1, As0, Bs0, 7);

#undef STEP
#undef STAGE
#undef COMPUTE
#undef WAITV
#undef BAR
#undef SCHED0

  // ---------------- Epilogue ----------------
  // acc[i][j][r] holds C[m0 + mw + i*16 + quad*4 + r][n0 + nw + j*16 + l16].
  const int bs = n0 / FRAMES;
  const int os = n0 - bs * FRAMES;
  const bool fast = (os + 128 <= FRAMES) && (n0 + 128 <= COLS);

  if (fast) {
    // Swizzled dump: element (row,col) stored at col^sw, sw=(row&12)<<2.
    // Dump: sw==quad*16 -> quads {0,2}/{1,3} in opposite bank halves
    // (2-way, free). Read Ct[row*128 + (lane^sw)] == element (row,lane)
    // (de-swizzle happens HERE, exactly once); banks = perm of 0..63 ->
    // 2 lanes/bank (free). Store plainly: contiguous 256-B spans.
    float* Ct = (float*)SMEM;
#pragma unroll
    for (int i = 0; i < 4; ++i) {
#pragma unroll
      for (int j = 0; j < 4; ++j) {
        const int Lr0 = mw + i * 16 + quad * 4;
        const int Lc = nw + j * 16 + l16;
#pragma unroll
        for (int r = 0; r < 4; ++r) {
          const int row = Lr0 + r;
          Ct[row * 128 + (Lc ^ ((row & 12) << 2))] = acc[i][j][r];
        }
      }
    }
    __syncthreads();
    float* const obase = out + (size_t)bs * N_ * FRAMES + os;
#pragma unroll 4
    for (int it2 = 0; it2 < 32; ++it2) {
      const int row = wid * 32 + it2;     // local row 0..127
      const int sw = (row & 12) << 2;
      const int grow = m0 + row;          // global row < 512
      const float v0 = Ct[row * 128 + (lane ^ sw)];          // = C[grow][os+lane]
      const float v1 = Ct[row * 128 + ((64 + lane) ^ sw)];   // = C[grow][os+64+lane]
      float* rp = obase + (size_t)grow * FRAMES;
      rp[lane] = v0;
      rp[64 + lane] = v1;
    }
  } else {
    // Straddle/tail blocks (~64/1028): verified scalar path.
#pragma unroll
    for (int i = 0; i < 4; ++i) {
#pragma unroll
      for (int j = 0; j < 4; ++j) {
        int col = n0 + nw + j * 16 + l16;
        if (col < COLS) {
          int b = col / FRAMES;
          int o = col - b * FRAMES;
          int rowb = m0 + mw + i * 16 + quad * 4;
          float* op = out + (size_t)b * N_ * FRAMES + (size_t)rowb * FRAMES + o;
#pragma unroll
          for (int r = 0; r < 4; ++r) op[(size_t)r * FRAMES] = acc[i][j][r];
        }
      }
    }
  }
}

// ---------------- Fallback: direct fp32 conv (if ws too small) --------------
__global__ void naive_conv(const float* __restrict__ x, const float* __restrict__ f,
                           float* __restrict__ out) {
  int col = blockIdx.x;
  int k = threadIdx.x;
  __shared__ float win[1024];
  int b = col / FRAMES;
  int o = col - b * FRAMES;
  const float* xb = x + (size_t)b * LEN;
  int g = o * N_ - N_;
  for (int t = threadIdx.x; t < 1024; t += 512) {
    int i = g + t;
    win[t] = (i >= 0 && i < LEN) ? xb[i] : 0.0f;
  }
  __syncthreads();
  float s = 0.0f;
  const float* fk = f + (size_t)k * 1024;
  for (int t = 0; t < 1024; ++t) s += win[t] * fk[t];
  out[(size_t)b * N_ * FRAMES + (size_t)k * FRAMES + o] = s;
}

extern "C" void kernel_launch(void* const* d_in, const int* in_sizes, int n_in,
                              void* d_out, int out_size, void* d_ws, size_t ws_size,
                              hipStream_t stream) {
  const float* x = (const float*)d_in[0];
  const float* f = (const float*)d_in[1];
  float* out = (float*)d_out;

  const size_t elems_D = (size_t)512 * 512;
  const size_t elems_V = (size_t)COLS_PAD * KF;
  const size_t need = (elems_D + elems_V) * sizeof(_Float16);

  if (ws_size < need) {
    naive_conv<<<COLS, 512, 0, stream>>>(x, f, out);
    return;
  }

  _Float16* D = (_Float16*)d_ws;
  _Float16* V = D + elems_D;

  prep_filter<<<256, 256, 0, stream>>>(f, D);
  fold_x<<<COLS_PAD / 4, 256, 0, stream>>>(x, V);
  // Grid 1056 = 132*8: covers nt=0..256, m=0..3 (max id 1048); tail exits.
  gemm_fold<<<1056, 256, 0, stream>>>(D, V, out);
}